// Round 2
// baseline (59001.703 us; speedup 1.0000x reference)
//
#include <hip/hip_runtime.h>
#include <hip/hip_cooperative_groups.h>
#include <math.h>

namespace cg = cooperative_groups;

#define NN 4096
#define DD 2048
#define KTOP 1024

// ---- packed (value, index) for argmax with first-occurrence tie-break ----
__device__ __forceinline__ unsigned long long packvi(float v, int idx) {
  unsigned u = __float_as_uint(v);
  u = (u & 0x80000000u) ? ~u : (u | 0x80000000u);  // monotone float->uint map
  return ((unsigned long long)u << 32) | (unsigned long long)(0xFFFFFFFFu - (unsigned)idx);
}
__device__ __forceinline__ float unpackv(unsigned long long p) {
  unsigned u = (unsigned)(p >> 32);
  u = (u & 0x80000000u) ? (u & 0x7FFFFFFFu) : ~u;
  return __uint_as_float(u);
}
__device__ __forceinline__ int unpacki(unsigned long long p) {
  return (int)(0xFFFFFFFFu - (unsigned)(p & 0xFFFFFFFFull));
}

// ---- 1) row L2-normalize + diag of similarity (sum of squares of stored values) ----
__global__ __launch_bounds__(256) void k_normalize(const float* __restrict__ X,
                                                   float* __restrict__ Xn,
                                                   float* __restrict__ diag) {
  __shared__ float red[4];
  const int row = blockIdx.x;
  const int tid = threadIdx.x;
  const float4* x4 = (const float4*)(X + (size_t)row * DD);
  float4 a = x4[tid];
  float4 b = x4[tid + 256];
  float ss = a.x*a.x + a.y*a.y + a.z*a.z + a.w*a.w
           + b.x*b.x + b.y*b.y + b.z*b.z + b.w*b.w;
  #pragma unroll
  for (int m = 1; m < 64; m <<= 1) ss += __shfl_xor(ss, m, 64);
  if ((tid & 63) == 0) red[tid >> 6] = ss;
  __syncthreads();
  const float tot = red[0] + red[1] + red[2] + red[3];
  const float nrm = sqrtf(tot);
  float4 ya, yb;
  ya.x = a.x / nrm; ya.y = a.y / nrm; ya.z = a.z / nrm; ya.w = a.w / nrm;
  yb.x = b.x / nrm; yb.y = b.y / nrm; yb.z = b.z / nrm; yb.w = b.w / nrm;
  float4* y4 = (float4*)(Xn + (size_t)row * DD);
  y4[tid] = ya; y4[tid + 256] = yb;
  float s2 = ya.x*ya.x + ya.y*ya.y + ya.z*ya.z + ya.w*ya.w
           + yb.x*yb.x + yb.y*yb.y + yb.z*yb.z + yb.w*yb.w;
  #pragma unroll
  for (int m = 1; m < 64; m <<= 1) s2 += __shfl_xor(s2, m, 64);
  __syncthreads();
  if ((tid & 63) == 0) red[tid >> 6] = s2;
  __syncthreads();
  if (tid == 0) diag[row] = red[0] + red[1] + red[2] + red[3];
}

// ---- 2) relevance normalization + initial di2s (matches reference op order) ----
__global__ __launch_bounds__(256) void k_relprep(const float* __restrict__ attn,
                                                 const float* __restrict__ diag,
                                                 float* __restrict__ rel,
                                                 float* __restrict__ di2s) {
  __shared__ float smn[4], smx[4];
  const int tid = threadIdx.x;
  float amin = INFINITY, amax = -INFINITY;
  for (int n = tid; n < NN; n += 256) {
    float v = attn[n];
    amin = fminf(amin, v);
    amax = fmaxf(amax, v);
  }
  #pragma unroll
  for (int m = 1; m < 64; m <<= 1) {
    amin = fminf(amin, __shfl_xor(amin, m, 64));
    amax = fmaxf(amax, __shfl_xor(amax, m, 64));
  }
  if ((tid & 63) == 0) { smn[tid >> 6] = amin; smx[tid >> 6] = amax; }
  __syncthreads();
  amin = fminf(fminf(smn[0], smn[1]), fminf(smn[2], smn[3]));
  amax = fmaxf(fmaxf(smx[0], smx[1]), fmaxf(smx[2], smx[3]));
  // relevance = -attn; rmin = -amax, rmax = -amin
  const float denom = amax - amin;                 // rmax - rmin
  for (int n = tid; n < NN; n += 256) {
    float r = (amax - attn[n]) + 1e-6f;            // (rel - rel.min()) + EPS
    float rl = r / denom;
    rel[n] = rl;
    di2s[n] = (rl * diag[n]) * rl;                 // (rel_n * sim_nn) * rel_n
  }
}

// ---- 3) K = diag(rel) * (Xn Xn^T) * diag(rel), symmetric: compute bi<=bj, mirror ----
__global__ __launch_bounds__(256) void k_syrk(const float* __restrict__ Xn,
                                              const float* __restrict__ rel,
                                              float* __restrict__ Kmat) {
  const int bj = blockIdx.x, bi = blockIdx.y;
  if (bi > bj) return;
  __shared__ float As[32][128];
  __shared__ float Bs[32][128];
  const int tid = threadIdx.x;
  const int tx = tid & 15, ty = tid >> 4;
  float acc[8][8];
  #pragma unroll
  for (int y = 0; y < 8; ++y)
    #pragma unroll
    for (int x = 0; x < 8; ++x) acc[y][x] = 0.f;
  const int row0 = bi * 128, col0 = bj * 128;
  const int lr = tid >> 3;        // 0..31
  const int lk = (tid & 7) * 4;   // 0,4,...,28
  for (int kk = 0; kk < DD; kk += 32) {
    __syncthreads();
    #pragma unroll
    for (int it = 0; it < 4; ++it) {
      const int r = lr + it * 32;
      float4 va = *(const float4*)(Xn + (size_t)(row0 + r) * DD + kk + lk);
      As[lk + 0][r] = va.x; As[lk + 1][r] = va.y; As[lk + 2][r] = va.z; As[lk + 3][r] = va.w;
      float4 vb = *(const float4*)(Xn + (size_t)(col0 + r) * DD + kk + lk);
      Bs[lk + 0][r] = vb.x; Bs[lk + 1][r] = vb.y; Bs[lk + 2][r] = vb.z; Bs[lk + 3][r] = vb.w;
    }
    __syncthreads();
    #pragma unroll
    for (int k = 0; k < 32; ++k) {
      float af[8], bf[8];
      *(float4*)&af[0] = *(const float4*)&As[k][ty * 8];
      *(float4*)&af[4] = *(const float4*)&As[k][ty * 8 + 4];
      *(float4*)&bf[0] = *(const float4*)&Bs[k][tx * 8];
      *(float4*)&bf[4] = *(const float4*)&Bs[k][tx * 8 + 4];
      #pragma unroll
      for (int y = 0; y < 8; ++y)
        #pragma unroll
        for (int x = 0; x < 8; ++x) acc[y][x] = fmaf(af[y], bf[x], acc[y][x]);
    }
  }
  float relr[8], relc[8];
  #pragma unroll
  for (int y = 0; y < 8; ++y) relr[y] = rel[row0 + ty * 8 + y];
  #pragma unroll
  for (int x = 0; x < 8; ++x) relc[x] = rel[col0 + tx * 8 + x];
  #pragma unroll
  for (int y = 0; y < 8; ++y) {
    const size_t rbase = (size_t)(row0 + ty * 8 + y) * NN + col0 + tx * 8;
    #pragma unroll
    for (int x = 0; x < 8; ++x)
      Kmat[rbase + x] = (relr[y] * acc[y][x]) * relc[x];
  }
  if (bi != bj) {
    #pragma unroll
    for (int x = 0; x < 8; ++x) {
      const size_t rbase = (size_t)(col0 + tx * 8 + x) * NN + row0 + ty * 8;
      #pragma unroll
      for (int y = 0; y < 8; ++y)
        Kmat[rbase + y] = (relc[x] * acc[y][x]) * relr[y];
    }
  }
}

// ---- 4) persistent greedy DPP loop: one grid.sync per step ----
// 256 blocks x 256 threads; block b owns columns [b*16, b*16+16).
// di2s register-resident in lanes 0..15 of each block. cis stored column-major (cisT[N][KTOP]).
__global__ __launch_bounds__(256) void k_greedy(const float* __restrict__ Kmat,
                                                const float* __restrict__ di2s_in,
                                                float* __restrict__ cisT,
                                                unsigned long long* __restrict__ partials,
                                                int* __restrict__ selOut) {
  cg::grid_group grid = cg::this_grid();
  __shared__ float cj[KTOP];
  __shared__ float sred[16];
  __shared__ unsigned long long wred[4];
  __shared__ int jsh;
  __shared__ float djsh;
  const int b = blockIdx.x;
  const int tid = threadIdx.x;
  const int c0 = b * 16;

  float dreg = -INFINITY;
  if (tid < 16) dreg = di2s_in[c0 + tid];
  if (tid < 16) {
    unsigned long long pk = packvi(dreg, c0 + tid);
    #pragma unroll
    for (int m = 1; m < 16; m <<= 1) {
      unsigned long long o = __shfl_xor(pk, m, 64);
      if (o > pk) pk = o;
    }
    if (tid == 0) partials[b] = pk;
  }
  __threadfence();
  grid.sync();

  const int col = tid >> 4;   // 0..15 : which of my 16 columns
  const int tg  = tid & 15;   // 0..15 : position within the t-group
  const float* __restrict__ ccol = cisT + (size_t)(c0 + col) * KTOP;

  for (int i = 0; i < KTOP; ++i) {
    // global argmax from the 256 per-block partials (redundant in every block)
    unsigned long long pk = partials[tid];
    #pragma unroll
    for (int m = 1; m < 64; m <<= 1) {
      unsigned long long o = __shfl_xor(pk, m, 64);
      if (o > pk) pk = o;
    }
    if ((tid & 63) == 0) wred[tid >> 6] = pk;
    __syncthreads();
    if (tid == 0) {
      unsigned long long p0 = wred[0];
      if (wred[1] > p0) p0 = wred[1];
      if (wred[2] > p0) p0 = wred[2];
      if (wred[3] > p0) p0 = wred[3];
      jsh  = unpacki(p0);
      djsh = unpackv(p0);
      if (b == 0) selOut[i] = jsh;
    }
    __syncthreads();
    const int j = jsh;
    const float dj = djsh;

    // stage cj = cisT[j, 0..i) into LDS (contiguous row)
    for (int t = tid; t < i; t += 256) cj[t] = cisT[(size_t)j * KTOP + t];
    __syncthreads();

    // GEMV: s[m] = sum_t cj[t] * cis[t][m] for my 16 columns
    float acc = 0.f;
    for (int t = tg; t < i; t += 16) acc = fmaf(cj[t], ccol[t], acc);
    #pragma unroll
    for (int m = 1; m < 16; m <<= 1) acc += __shfl_xor(acc, m, 64);
    if (tg == 0) sred[col] = acc;
    __syncthreads();

    // epilogue: eis, cis write, di2s update, next-step partial argmax
    if (tid < 16) {
      const int mm = c0 + tid;
      const float s = sred[tid];
      const float kjm = Kmat[(size_t)j * NN + mm];
      const float e = (kjm - s) / sqrtf(dj);
      cisT[(size_t)mm * KTOP + i] = e;
      float nd = dreg - e * e;
      if (mm == j) nd = -INFINITY;
      dreg = nd;
      unsigned long long pk2 = packvi(nd, mm);
      #pragma unroll
      for (int m = 1; m < 16; m <<= 1) {
        unsigned long long o = __shfl_xor(pk2, m, 64);
        if (o > pk2) pk2 = o;
      }
      if (tid == 0) partials[b] = pk2;
    }
    __threadfence();
    grid.sync();
  }
}

extern "C" void kernel_launch(void* const* d_in, const int* in_sizes, int n_in,
                              void* d_out, int out_size, void* d_ws, size_t ws_size,
                              hipStream_t stream) {
  (void)in_sizes; (void)n_in; (void)out_size; (void)ws_size;
  const float* X    = (const float*)d_in[0];
  const float* attn = (const float*)d_in[1];
  int* sel = (int*)d_out;

  char* w = (char*)d_ws;
  float* Xn   = (float*)(w);                                    // 33,554,432 B
  float* Kmat = (float*)(w + 33554432ull);                      // 67,108,864 B
  float* cisT = (float*)(w + 33554432ull + 67108864ull);        // 16,777,216 B
  float* rel  = (float*)(w + 117440512ull);                     // 16 KB
  float* di2s = (float*)(w + 117440512ull + 16384ull);          // 16 KB
  float* diag = (float*)(w + 117440512ull + 32768ull);          // 16 KB
  unsigned long long* partials = (unsigned long long*)(w + 117440512ull + 49152ull); // 2 KB

  k_normalize<<<dim3(NN), dim3(256), 0, stream>>>(X, Xn, diag);
  k_relprep<<<dim3(1), dim3(256), 0, stream>>>(attn, diag, rel, di2s);
  k_syrk<<<dim3(32, 32), dim3(256), 0, stream>>>(Xn, rel, Kmat);

  void* args[] = { (void*)&Kmat, (void*)&di2s, (void*)&cisT, (void*)&partials, (void*)&sel };
  hipLaunchCooperativeKernel((void*)k_greedy, dim3(256), dim3(256), args, 0u, stream);
}

// Round 3
// 31134.244 us; speedup vs baseline: 1.8951x; 1.8951x over previous
//
#include <hip/hip_runtime.h>
#include <hip/hip_cooperative_groups.h>
#include <math.h>

#define NN 4096
#define DD 2048
#define KTOP 1024
#define CIS_STRIDE 1040   // 1040 mod 32 == 16 -> 2-way LDS bank aliasing (free)

// packed (value, index, step-tag):  [mono_val:32][unused:8][inv_idx:12][tag:12]
// equal tags across a round => max() compares (val, inv_idx); inv_idx gives
// first-occurrence (smallest index) tie-break like jnp.argmax.
__device__ __forceinline__ unsigned long long packvit(float v, int idx, int tag) {
  unsigned u = __float_as_uint(v);
  u = (u & 0x80000000u) ? ~u : (u | 0x80000000u);  // monotone float->uint
  unsigned long long inv = (unsigned long long)(4095u - (unsigned)idx);
  return ((unsigned long long)u << 32) | (inv << 12) | (unsigned)tag;
}
__device__ __forceinline__ float unpackv(unsigned long long p) {
  unsigned u = (unsigned)(p >> 32);
  u = (u & 0x80000000u) ? (u & 0x7FFFFFFFu) : ~u;
  return __uint_as_float(u);
}
__device__ __forceinline__ int unpacki(unsigned long long p) {
  return 4095 - (int)((p >> 12) & 0xFFFull);
}

// ---- 1) row L2-normalize + diag of similarity ----
__global__ __launch_bounds__(256) void k_normalize(const float* __restrict__ X,
                                                   float* __restrict__ Xn,
                                                   float* __restrict__ diag) {
  __shared__ float red[4];
  const int row = blockIdx.x;
  const int tid = threadIdx.x;
  const float4* x4 = (const float4*)(X + (size_t)row * DD);
  float4 a = x4[tid];
  float4 b = x4[tid + 256];
  float ss = a.x*a.x + a.y*a.y + a.z*a.z + a.w*a.w
           + b.x*b.x + b.y*b.y + b.z*b.z + b.w*b.w;
  #pragma unroll
  for (int m = 1; m < 64; m <<= 1) ss += __shfl_xor(ss, m, 64);
  if ((tid & 63) == 0) red[tid >> 6] = ss;
  __syncthreads();
  const float tot = red[0] + red[1] + red[2] + red[3];
  const float nrm = sqrtf(tot);
  float4 ya, yb;
  ya.x = a.x / nrm; ya.y = a.y / nrm; ya.z = a.z / nrm; ya.w = a.w / nrm;
  yb.x = b.x / nrm; yb.y = b.y / nrm; yb.z = b.z / nrm; yb.w = b.w / nrm;
  float4* y4 = (float4*)(Xn + (size_t)row * DD);
  y4[tid] = ya; y4[tid + 256] = yb;
  float s2 = ya.x*ya.x + ya.y*ya.y + ya.z*ya.z + ya.w*ya.w
           + yb.x*yb.x + yb.y*yb.y + yb.z*yb.z + yb.w*yb.w;
  #pragma unroll
  for (int m = 1; m < 64; m <<= 1) s2 += __shfl_xor(s2, m, 64);
  __syncthreads();
  if ((tid & 63) == 0) red[tid >> 6] = s2;
  __syncthreads();
  if (tid == 0) diag[row] = red[0] + red[1] + red[2] + red[3];
}

// ---- 2) relevance normalization + initial di2s ----
__global__ __launch_bounds__(256) void k_relprep(const float* __restrict__ attn,
                                                 const float* __restrict__ diag,
                                                 float* __restrict__ rel,
                                                 float* __restrict__ di2s) {
  __shared__ float smn[4], smx[4];
  const int tid = threadIdx.x;
  float amin = INFINITY, amax = -INFINITY;
  for (int n = tid; n < NN; n += 256) {
    float v = attn[n];
    amin = fminf(amin, v);
    amax = fmaxf(amax, v);
  }
  #pragma unroll
  for (int m = 1; m < 64; m <<= 1) {
    amin = fminf(amin, __shfl_xor(amin, m, 64));
    amax = fmaxf(amax, __shfl_xor(amax, m, 64));
  }
  if ((tid & 63) == 0) { smn[tid >> 6] = amin; smx[tid >> 6] = amax; }
  __syncthreads();
  amin = fminf(fminf(smn[0], smn[1]), fminf(smn[2], smn[3]));
  amax = fmaxf(fmaxf(smx[0], smx[1]), fmaxf(smx[2], smx[3]));
  const float denom = amax - amin;
  for (int n = tid; n < NN; n += 256) {
    float r = (amax - attn[n]) + 1e-6f;
    float rl = r / denom;
    rel[n] = rl;
    di2s[n] = (rl * diag[n]) * rl;
  }
}

// ---- 3) K = diag(rel)*(Xn Xn^T)*diag(rel), symmetric ----
__global__ __launch_bounds__(256) void k_syrk(const float* __restrict__ Xn,
                                              const float* __restrict__ rel,
                                              float* __restrict__ Kmat) {
  const int bj = blockIdx.x, bi = blockIdx.y;
  if (bi > bj) return;
  __shared__ float As[32][128];
  __shared__ float Bs[32][128];
  const int tid = threadIdx.x;
  const int tx = tid & 15, ty = tid >> 4;
  float acc[8][8];
  #pragma unroll
  for (int y = 0; y < 8; ++y)
    #pragma unroll
    for (int x = 0; x < 8; ++x) acc[y][x] = 0.f;
  const int row0 = bi * 128, col0 = bj * 128;
  const int lr = tid >> 3;
  const int lk = (tid & 7) * 4;
  for (int kk = 0; kk < DD; kk += 32) {
    __syncthreads();
    #pragma unroll
    for (int it = 0; it < 4; ++it) {
      const int r = lr + it * 32;
      float4 va = *(const float4*)(Xn + (size_t)(row0 + r) * DD + kk + lk);
      As[lk + 0][r] = va.x; As[lk + 1][r] = va.y; As[lk + 2][r] = va.z; As[lk + 3][r] = va.w;
      float4 vb = *(const float4*)(Xn + (size_t)(col0 + r) * DD + kk + lk);
      Bs[lk + 0][r] = vb.x; Bs[lk + 1][r] = vb.y; Bs[lk + 2][r] = vb.z; Bs[lk + 3][r] = vb.w;
    }
    __syncthreads();
    #pragma unroll
    for (int k = 0; k < 32; ++k) {
      float af[8], bf[8];
      *(float4*)&af[0] = *(const float4*)&As[k][ty * 8];
      *(float4*)&af[4] = *(const float4*)&As[k][ty * 8 + 4];
      *(float4*)&bf[0] = *(const float4*)&Bs[k][tx * 8];
      *(float4*)&bf[4] = *(const float4*)&Bs[k][tx * 8 + 4];
      #pragma unroll
      for (int y = 0; y < 8; ++y)
        #pragma unroll
        for (int x = 0; x < 8; ++x) acc[y][x] = fmaf(af[y], bf[x], acc[y][x]);
    }
  }
  float relr[8], relc[8];
  #pragma unroll
  for (int y = 0; y < 8; ++y) relr[y] = rel[row0 + ty * 8 + y];
  #pragma unroll
  for (int x = 0; x < 8; ++x) relc[x] = rel[col0 + tx * 8 + x];
  #pragma unroll
  for (int y = 0; y < 8; ++y) {
    const size_t rbase = (size_t)(row0 + ty * 8 + y) * NN + col0 + tx * 8;
    #pragma unroll
    for (int x = 0; x < 8; ++x)
      Kmat[rbase + x] = (relr[y] * acc[y][x]) * relc[x];
  }
  if (bi != bj) {
    #pragma unroll
    for (int x = 0; x < 8; ++x) {
      const size_t rbase = (size_t)(col0 + tx * 8 + x) * NN + row0 + ty * 8;
      #pragma unroll
      for (int y = 0; y < 8; ++y)
        Kmat[rbase + y] = (relc[x] * acc[y][x]) * relr[y];
    }
  }
}

// ---- 4) persistent greedy loop, NO grid.sync: the tagged partials exchange
// IS the barrier. Block b owns columns [b*16, b*16+16); its cis columns live
// in LDS; cisT (global, row-major [N][KTOP]) exists only for the cj exchange.
__global__ __launch_bounds__(256) void k_greedy(const float* __restrict__ Kmat,
                                                const float* __restrict__ di2s_in,
                                                float* __restrict__ cisT,
                                                unsigned long long* __restrict__ partials, // [2][256]
                                                int* __restrict__ selOut) {
  __shared__ float cisL[16 * CIS_STRIDE];  // 66.5 KB: my 16 columns
  __shared__ float cjL[KTOP];
  __shared__ float sred[16];
  __shared__ unsigned long long wred[4];
  __shared__ int jsh;
  __shared__ float djsh;
  const int b = blockIdx.x;
  const int tid = threadIdx.x;
  const int c0 = b * 16;
  const int col = tid >> 4;   // 0..15: which of my 16 columns
  const int tg  = tid & 15;   // 0..15: position within t-group

  // initial publish (round 0)
  float dreg = -INFINITY;
  if (tid < 16) {
    dreg = di2s_in[c0 + tid];
    unsigned long long pk = packvit(dreg, c0 + tid, 0);
    #pragma unroll
    for (int m = 1; m < 16; m <<= 1) {
      unsigned long long o = __shfl_xor(pk, m, 64);
      if (o > pk) pk = o;
    }
    if (tid == 0)
      __hip_atomic_store(&partials[b], pk, __ATOMIC_RELEASE, __HIP_MEMORY_SCOPE_AGENT);
  }

  for (int i = 0; i < KTOP; ++i) {
    // -- fused barrier + argmax fan-in: spin until my word carries tag i --
    unsigned long long* slotp = partials + (size_t)(i & 1) * 256;
    unsigned long long pk;
    do {
      pk = __hip_atomic_load(&slotp[tid], __ATOMIC_ACQUIRE, __HIP_MEMORY_SCOPE_AGENT);
    } while ((unsigned)(pk & 0xFFFull) != (unsigned)i);
    #pragma unroll
    for (int m = 1; m < 64; m <<= 1) {
      unsigned long long o = __shfl_xor(pk, m, 64);
      if (o > pk) pk = o;
    }
    if ((tid & 63) == 0) wred[tid >> 6] = pk;
    __syncthreads();
    if (tid == 0) {
      unsigned long long p0 = wred[0];
      if (wred[1] > p0) p0 = wred[1];
      if (wred[2] > p0) p0 = wred[2];
      if (wred[3] > p0) p0 = wred[3];
      jsh  = unpacki(p0);
      djsh = unpackv(p0);
      if (b == 0) selOut[i] = jsh;
    }
    __syncthreads();
    const int j = jsh;
    const float dj = djsh;

    // issue Kmat load early; it retires under the cj stage + GEMV
    float kjm = 0.f;
    if (tid < 16) kjm = Kmat[(size_t)j * NN + c0 + tid];

    // stage cj = cisT[j][0..i) into LDS
    const float* __restrict__ rowj = cisT + (size_t)j * KTOP;
    for (int t = tid; t < i; t += 256) cjL[t] = rowj[t];
    __syncthreads();

    // GEMV from LDS: s[col] = sum_t cj[t] * cisL[col][t]
    float acc = 0.f;
    for (int t = tg; t < i; t += 16)
      acc = fmaf(cjL[t], cisL[col * CIS_STRIDE + t], acc);
    #pragma unroll
    for (int m = 1; m < 16; m <<= 1) acc += __shfl_xor(acc, m, 64);
    if (tg == 0) sred[col] = acc;
    __syncthreads();

    // epilogue (wave 0, lanes 0..15): eis, stores, di2s update, next publish.
    // Release store is by the SAME wave that did the cisT stores -> ordered.
    if (tid < 16) {
      const int mm = c0 + tid;
      const float e = (kjm - sred[tid]) / sqrtf(dj);
      cisT[(size_t)mm * KTOP + i] = e;
      cisL[tid * CIS_STRIDE + i] = e;
      float nd = dreg - e * e;
      if (mm == j) nd = -INFINITY;
      dreg = nd;
      unsigned long long pk2 = packvit(nd, mm, i + 1);
      #pragma unroll
      for (int m = 1; m < 16; m <<= 1) {
        unsigned long long o = __shfl_xor(pk2, m, 64);
        if (o > pk2) pk2 = o;
      }
      if (tid == 0)
        __hip_atomic_store(&partials[((i + 1) & 1) * 256 + b], pk2,
                           __ATOMIC_RELEASE, __HIP_MEMORY_SCOPE_AGENT);
    }
  }
}

extern "C" void kernel_launch(void* const* d_in, const int* in_sizes, int n_in,
                              void* d_out, int out_size, void* d_ws, size_t ws_size,
                              hipStream_t stream) {
  (void)in_sizes; (void)n_in; (void)out_size; (void)ws_size;
  const float* X    = (const float*)d_in[0];
  const float* attn = (const float*)d_in[1];
  int* sel = (int*)d_out;

  char* w = (char*)d_ws;
  float* Xn   = (float*)(w);                                    // 32 MB
  float* Kmat = (float*)(w + 33554432ull);                      // 64 MB
  float* cisT = (float*)(w + 33554432ull + 67108864ull);        // 16 MB
  float* rel  = (float*)(w + 117440512ull);                     // 16 KB
  float* di2s = (float*)(w + 117440512ull + 16384ull);          // 16 KB
  float* diag = (float*)(w + 117440512ull + 32768ull);          // 16 KB
  unsigned long long* partials = (unsigned long long*)(w + 117440512ull + 49152ull); // 4 KB

  k_normalize<<<dim3(NN), dim3(256), 0, stream>>>(X, Xn, diag);
  k_relprep<<<dim3(1), dim3(256), 0, stream>>>(attn, diag, rel, di2s);
  k_syrk<<<dim3(32, 32), dim3(256), 0, stream>>>(Xn, rel, Kmat);

  // cooperative launch only for the co-residency guarantee; no grid.sync inside
  void* args[] = { (void*)&Kmat, (void*)&di2s, (void*)&cisT, (void*)&partials, (void*)&sel };
  hipLaunchCooperativeKernel((void*)k_greedy, dim3(256), dim3(256), args, 0u, stream);
}

// Round 4
// 9227.739 us; speedup vs baseline: 6.3940x; 3.3740x over previous
//
#include <hip/hip_runtime.h>
#include <hip/hip_cooperative_groups.h>
#include <math.h>

#define NN 4096
#define DD 2048
#define KTOP 1024
#define CIS_STRIDE 1040   // 1040 mod 32 == 16 -> 2-way LDS bank aliasing (free)

// packed (value, index, step-tag):  [mono_val:32][zero:8][inv_idx:12][tag:12]
// equal tags across a round => max() compares (val, inv_idx); inv_idx gives
// first-occurrence (smallest index) tie-break like jnp.argmax.
__device__ __forceinline__ unsigned long long packvit(float v, int idx, int tag) {
  unsigned u = __float_as_uint(v);
  u = (u & 0x80000000u) ? ~u : (u | 0x80000000u);  // monotone float->uint
  unsigned long long inv = (unsigned long long)(4095u - (unsigned)idx);
  return ((unsigned long long)u << 32) | (inv << 12) | (unsigned)tag;
}
__device__ __forceinline__ float unpackv(unsigned long long p) {
  unsigned u = (unsigned)(p >> 32);
  u = (u & 0x80000000u) ? (u & 0x7FFFFFFFu) : ~u;
  return __uint_as_float(u);
}
__device__ __forceinline__ int unpacki(unsigned long long p) {
  return 4095 - (int)((p >> 12) & 0xFFFull);
}

// ---- 1) row L2-normalize + diag of similarity ----
__global__ __launch_bounds__(256) void k_normalize(const float* __restrict__ X,
                                                   float* __restrict__ Xn,
                                                   float* __restrict__ diag) {
  __shared__ float red[4];
  const int row = blockIdx.x;
  const int tid = threadIdx.x;
  const float4* x4 = (const float4*)(X + (size_t)row * DD);
  float4 a = x4[tid];
  float4 b = x4[tid + 256];
  float ss = a.x*a.x + a.y*a.y + a.z*a.z + a.w*a.w
           + b.x*b.x + b.y*b.y + b.z*b.z + b.w*b.w;
  #pragma unroll
  for (int m = 1; m < 64; m <<= 1) ss += __shfl_xor(ss, m, 64);
  if ((tid & 63) == 0) red[tid >> 6] = ss;
  __syncthreads();
  const float tot = red[0] + red[1] + red[2] + red[3];
  const float nrm = sqrtf(tot);
  float4 ya, yb;
  ya.x = a.x / nrm; ya.y = a.y / nrm; ya.z = a.z / nrm; ya.w = a.w / nrm;
  yb.x = b.x / nrm; yb.y = b.y / nrm; yb.z = b.z / nrm; yb.w = b.w / nrm;
  float4* y4 = (float4*)(Xn + (size_t)row * DD);
  y4[tid] = ya; y4[tid + 256] = yb;
  float s2 = ya.x*ya.x + ya.y*ya.y + ya.z*ya.z + ya.w*ya.w
           + yb.x*yb.x + yb.y*yb.y + yb.z*yb.z + yb.w*yb.w;
  #pragma unroll
  for (int m = 1; m < 64; m <<= 1) s2 += __shfl_xor(s2, m, 64);
  __syncthreads();
  if ((tid & 63) == 0) red[tid >> 6] = s2;
  __syncthreads();
  if (tid == 0) diag[row] = red[0] + red[1] + red[2] + red[3];
}

// ---- 2) relevance normalization + initial di2s ----
__global__ __launch_bounds__(256) void k_relprep(const float* __restrict__ attn,
                                                 const float* __restrict__ diag,
                                                 float* __restrict__ rel,
                                                 float* __restrict__ di2s) {
  __shared__ float smn[4], smx[4];
  const int tid = threadIdx.x;
  float amin = INFINITY, amax = -INFINITY;
  for (int n = tid; n < NN; n += 256) {
    float v = attn[n];
    amin = fminf(amin, v);
    amax = fmaxf(amax, v);
  }
  #pragma unroll
  for (int m = 1; m < 64; m <<= 1) {
    amin = fminf(amin, __shfl_xor(amin, m, 64));
    amax = fmaxf(amax, __shfl_xor(amax, m, 64));
  }
  if ((tid & 63) == 0) { smn[tid >> 6] = amin; smx[tid >> 6] = amax; }
  __syncthreads();
  amin = fminf(fminf(smn[0], smn[1]), fminf(smn[2], smn[3]));
  amax = fmaxf(fmaxf(smx[0], smx[1]), fmaxf(smx[2], smx[3]));
  const float denom = amax - amin;
  for (int n = tid; n < NN; n += 256) {
    float r = (amax - attn[n]) + 1e-6f;
    float rl = r / denom;
    rel[n] = rl;
    di2s[n] = (rl * diag[n]) * rl;
  }
}

// ---- 3) K = diag(rel)*(Xn Xn^T)*diag(rel), symmetric ----
__global__ __launch_bounds__(256) void k_syrk(const float* __restrict__ Xn,
                                              const float* __restrict__ rel,
                                              float* __restrict__ Kmat) {
  const int bj = blockIdx.x, bi = blockIdx.y;
  if (bi > bj) return;
  __shared__ float As[32][128];
  __shared__ float Bs[32][128];
  const int tid = threadIdx.x;
  const int tx = tid & 15, ty = tid >> 4;
  float acc[8][8];
  #pragma unroll
  for (int y = 0; y < 8; ++y)
    #pragma unroll
    for (int x = 0; x < 8; ++x) acc[y][x] = 0.f;
  const int row0 = bi * 128, col0 = bj * 128;
  const int lr = tid >> 3;
  const int lk = (tid & 7) * 4;
  for (int kk = 0; kk < DD; kk += 32) {
    __syncthreads();
    #pragma unroll
    for (int it = 0; it < 4; ++it) {
      const int r = lr + it * 32;
      float4 va = *(const float4*)(Xn + (size_t)(row0 + r) * DD + kk + lk);
      As[lk + 0][r] = va.x; As[lk + 1][r] = va.y; As[lk + 2][r] = va.z; As[lk + 3][r] = va.w;
      float4 vb = *(const float4*)(Xn + (size_t)(col0 + r) * DD + kk + lk);
      Bs[lk + 0][r] = vb.x; Bs[lk + 1][r] = vb.y; Bs[lk + 2][r] = vb.z; Bs[lk + 3][r] = vb.w;
    }
    __syncthreads();
    #pragma unroll
    for (int k = 0; k < 32; ++k) {
      float af[8], bf[8];
      *(float4*)&af[0] = *(const float4*)&As[k][ty * 8];
      *(float4*)&af[4] = *(const float4*)&As[k][ty * 8 + 4];
      *(float4*)&bf[0] = *(const float4*)&Bs[k][tx * 8];
      *(float4*)&bf[4] = *(const float4*)&Bs[k][tx * 8 + 4];
      #pragma unroll
      for (int y = 0; y < 8; ++y)
        #pragma unroll
        for (int x = 0; x < 8; ++x) acc[y][x] = fmaf(af[y], bf[x], acc[y][x]);
    }
  }
  float relr[8], relc[8];
  #pragma unroll
  for (int y = 0; y < 8; ++y) relr[y] = rel[row0 + ty * 8 + y];
  #pragma unroll
  for (int x = 0; x < 8; ++x) relc[x] = rel[col0 + tx * 8 + x];
  #pragma unroll
  for (int y = 0; y < 8; ++y) {
    const size_t rbase = (size_t)(row0 + ty * 8 + y) * NN + col0 + tx * 8;
    #pragma unroll
    for (int x = 0; x < 8; ++x)
      Kmat[rbase + x] = (relr[y] * acc[y][x]) * relc[x];
  }
  if (bi != bj) {
    #pragma unroll
    for (int x = 0; x < 8; ++x) {
      const size_t rbase = (size_t)(col0 + tx * 8 + x) * NN + row0 + ty * 8;
      #pragma unroll
      for (int y = 0; y < 8; ++y)
        Kmat[rbase + y] = (relc[x] * acc[y][x]) * relr[y];
    }
  }
}

// ---- 4) persistent greedy loop, fence-free reader protocol.
// Block b owns columns [b*16, b*16+16); columns live in LDS.
// Spin: relaxed agent loads on tagged words (no acquire, no invalidation storm).
// Data exchange (cj row, cisT): relaxed agent atomics (coherent, bypass local $).
// Writer order: cisT atomic stores -> release store of tagged partial (vmcnt drain).
__global__ __launch_bounds__(256) void k_greedy(const float* __restrict__ Kmat,
                                                const float* __restrict__ di2s_in,
                                                float* __restrict__ cisT,
                                                unsigned long long* __restrict__ partials, // [2][256]
                                                int* __restrict__ selOut) {
  __shared__ float cisL[16 * CIS_STRIDE];  // 66.5 KB: my 16 columns
  __shared__ float cjL[KTOP];
  __shared__ float sred[16];
  const int b = blockIdx.x;
  const int tid = threadIdx.x;
  const int lane = tid & 63;
  const int c0 = b * 16;
  const int col = tid >> 4;   // 0..15: which of my 16 columns
  const int tg  = tid & 15;   // 0..15: position within t-group

  // initial publish (round 0)
  float dreg = -INFINITY;
  if (tid < 16) {
    dreg = di2s_in[c0 + tid];
    unsigned long long pk = packvit(dreg, c0 + tid, 0);
    #pragma unroll
    for (int m = 1; m < 16; m <<= 1) {
      unsigned long long o = __shfl_xor(pk, m, 64);
      if (o > pk) pk = o;
    }
    if (tid == 0)
      __hip_atomic_store(&partials[b], pk, __ATOMIC_RELEASE, __HIP_MEMORY_SCOPE_AGENT);
  }

  for (int i = 0; i < KTOP; ++i) {
    // -- fused barrier + argmax: every wave scans all 256 tagged words --
    unsigned long long* slotp = partials + (size_t)(i & 1) * 256;
    const unsigned tagi = (unsigned)i;
    unsigned long long w0, w1, w2, w3;
    do {
      w0 = __hip_atomic_load(&slotp[lane],       __ATOMIC_RELAXED, __HIP_MEMORY_SCOPE_AGENT);
      w1 = __hip_atomic_load(&slotp[lane + 64],  __ATOMIC_RELAXED, __HIP_MEMORY_SCOPE_AGENT);
      w2 = __hip_atomic_load(&slotp[lane + 128], __ATOMIC_RELAXED, __HIP_MEMORY_SCOPE_AGENT);
      w3 = __hip_atomic_load(&slotp[lane + 192], __ATOMIC_RELAXED, __HIP_MEMORY_SCOPE_AGENT);
    } while ((unsigned)(w0 & 0xFFFull) != tagi || (unsigned)(w1 & 0xFFFull) != tagi ||
             (unsigned)(w2 & 0xFFFull) != tagi || (unsigned)(w3 & 0xFFFull) != tagi);
    unsigned long long pk = w0;
    if (w1 > pk) pk = w1;
    if (w2 > pk) pk = w2;
    if (w3 > pk) pk = w3;
    #pragma unroll
    for (int m = 1; m < 64; m <<= 1) {
      unsigned long long o = __shfl_xor(pk, m, 64);
      if (o > pk) pk = o;
    }
    const int j = unpacki(pk);
    const float dj = unpackv(pk);
    if (b == 0 && tid == 0) selOut[i] = j;

    // issue Kmat load early; retires under the cj stage
    float kjm = 0.f;
    if (tid < 16) kjm = Kmat[(size_t)j * NN + c0 + tid];

    // stage cj = cisT[j][0..i) into LDS via coherent relaxed loads
    const unsigned* __restrict__ rowj = (const unsigned*)(cisT + (size_t)j * KTOP);
    for (int t = tid; t < i; t += 256)
      ((unsigned*)cjL)[t] = __hip_atomic_load(&rowj[t], __ATOMIC_RELAXED, __HIP_MEMORY_SCOPE_AGENT);
    __syncthreads();

    // GEMV from LDS: s[col] = sum_t cj[t] * cisL[col][t]
    float acc = 0.f;
    for (int t = tg; t < i; t += 16)
      acc = fmaf(cjL[t], cisL[col * CIS_STRIDE + t], acc);
    #pragma unroll
    for (int m = 1; m < 16; m <<= 1) acc += __shfl_xor(acc, m, 64);
    if (tg == 0) sred[col] = acc;
    __syncthreads();

    // epilogue (wave 0, lanes 0..15): eis, stores, di2s update, next publish.
    // Release store is by the SAME wave that issued the cisT atomic stores ->
    // vmcnt drain orders them; readers need no acquire.
    if (tid < 16) {
      const int mm = c0 + tid;
      const float e = (kjm - sred[tid]) / sqrtf(dj);
      __hip_atomic_store((unsigned*)cisT + (size_t)mm * KTOP + i, __float_as_uint(e),
                         __ATOMIC_RELAXED, __HIP_MEMORY_SCOPE_AGENT);
      cisL[tid * CIS_STRIDE + i] = e;
      float nd = dreg - e * e;
      if (mm == j) nd = -INFINITY;
      dreg = nd;
      unsigned long long pk2 = packvit(nd, mm, i + 1);
      #pragma unroll
      for (int m = 1; m < 16; m <<= 1) {
        unsigned long long o = __shfl_xor(pk2, m, 64);
        if (o > pk2) pk2 = o;
      }
      if (tid == 0)
        __hip_atomic_store(&partials[((i + 1) & 1) * 256 + b], pk2,
                           __ATOMIC_RELEASE, __HIP_MEMORY_SCOPE_AGENT);
    }
  }
}

extern "C" void kernel_launch(void* const* d_in, const int* in_sizes, int n_in,
                              void* d_out, int out_size, void* d_ws, size_t ws_size,
                              hipStream_t stream) {
  (void)in_sizes; (void)n_in; (void)out_size; (void)ws_size;
  const float* X    = (const float*)d_in[0];
  const float* attn = (const float*)d_in[1];
  int* sel = (int*)d_out;

  char* w = (char*)d_ws;
  float* Xn   = (float*)(w);                                    // 32 MB
  float* Kmat = (float*)(w + 33554432ull);                      // 64 MB
  float* cisT = (float*)(w + 33554432ull + 67108864ull);        // 16 MB
  float* rel  = (float*)(w + 117440512ull);                     // 16 KB
  float* di2s = (float*)(w + 117440512ull + 16384ull);          // 16 KB
  float* diag = (float*)(w + 117440512ull + 32768ull);          // 16 KB
  unsigned long long* partials = (unsigned long long*)(w + 117440512ull + 49152ull); // 4 KB

  k_normalize<<<dim3(NN), dim3(256), 0, stream>>>(X, Xn, diag);
  k_relprep<<<dim3(1), dim3(256), 0, stream>>>(attn, diag, rel, di2s);
  k_syrk<<<dim3(32, 32), dim3(256), 0, stream>>>(Xn, rel, Kmat);

  // cooperative launch only for the co-residency guarantee; no grid.sync inside
  void* args[] = { (void*)&Kmat, (void*)&di2s, (void*)&cisT, (void*)&partials, (void*)&sel };
  hipLaunchCooperativeKernel((void*)k_greedy, dim3(256), dim3(256), args, 0u, stream);
}